// Round 7
// baseline (366.222 us; speedup 1.0000x reference)
//
#include <hip/hip_runtime.h>
#include <cstdint>
#include <cstddef>

// ---------------------------------------------------------------------------
// L4maAttention, fp16 pipeline:
//   cvt fp32->fp16 (hidden+Wq+Wk+Wv fused) -> fused QKV GEMM (global_load_lds,
//   swizzled LDS) -> aux_all (Wo cvt + RoPE q/k + cached-KV convert, fused) ->
//   flash attention (swapped QK^T lane-local softmax; K fragments loaded
//   global->reg software-pipelined (no K LDS, halves DS-pipe load); PV via
//   x16 MFMA fed by ds_read_b64_tr_b16; V dbuf in LDS; balanced q-tile remap)
//   -> O-proj GEMM -> d_out fp32.
// ---------------------------------------------------------------------------

typedef _Float16 f16;
typedef f16 f16x8 __attribute__((ext_vector_type(8)));
typedef f16 f16x4 __attribute__((ext_vector_type(4)));
typedef float f32x4 __attribute__((ext_vector_type(4)));

#define HIDN 4096
#define LCTX 3072
#define PASTN 2048
// 1/sqrt(128) * log2(e): QK^T computed in log2 domain (exp2-based softmax)
#define QK_SCALE_LOG2 0.12753102734366334f
#define RESC_THR 11.54f   /* defer-max threshold, log2 units (~8 nats) */

__device__ __forceinline__ f32x4 mfma16(f16x8 a, f16x8 b, f32x4 c) {
    return __builtin_amdgcn_mfma_f32_16x16x32_f16(a, b, c, 0, 0, 0);
}
__device__ __forceinline__ f32x4 mfma16k16(f16x4 a, f16x4 b, f32x4 c) {
    return __builtin_amdgcn_mfma_f32_16x16x16f16(a, b, c, 0, 0, 0);
}

// global -> LDS direct copy, 16B per lane. LDS dest = wave-uniform base +
// lane*16 (linear); per-lane permutation happens on the GLOBAL source address.
__device__ __forceinline__ void gl_lds16(const void* g, void* l) {
    auto gp = (const __attribute__((address_space(1))) unsigned int*)(uintptr_t)g;
    auto lp = (__attribute__((address_space(3))) unsigned int*)(uintptr_t)l;
    __builtin_amdgcn_global_load_lds(gp, lp, 16, 0, 0);
}

__device__ __forceinline__ uint32_t lds_lo(const void* p) {
    return (uint32_t)(uintptr_t)p;
}

// hardware transpose read (4x16 f16 subtile, column-major delivery)
#define TRRD(dst, va, OFF) \
    asm volatile("ds_read_b64_tr_b16 %0, %1 offset:" #OFF : "=v"(dst) : "v"(va))
#define WAITL(N) \
    asm volatile("s_waitcnt lgkmcnt(" #N ")" ::: "memory"); \
    __builtin_amdgcn_sched_barrier(0)

// ---------------------------------------------------------------------------
// fused fp32 -> fp16 conversions: hidden (1M x4), Wq (4M x4), Wk (1M x4),
// Wv (1M x4); grid = 28672 x 256 covers 7,340,032 float4s exactly.
// ---------------------------------------------------------------------------
__global__ void cvt_all(const float* __restrict__ hidden, const float* __restrict__ Wq,
                        const float* __restrict__ Wk, const float* __restrict__ Wv,
                        f16* __restrict__ h16, f16* __restrict__ w16)
{
    int i = blockIdx.x * 256 + threadIdx.x;
    const float* src; f16* dst; int off;
    if (i < 1048576)      { src = hidden; dst = h16; off = i; }
    else if (i < 5242880) { src = Wq; dst = w16; off = i - 1048576; }
    else if (i < 6291456) { src = Wk; dst = w16 + (size_t)4096 * 4096; off = i - 5242880; }
    else                  { src = Wv; dst = w16 + (size_t)5120 * 4096; off = i - 6291456; }
    f32x4 v = *(const f32x4*)(src + (size_t)off * 4);
    f16x4 h;
#pragma unroll
    for (int j = 0; j < 4; j++) h[j] = (f16)v[j];
    *(f16x4*)(dst + (size_t)off * 4) = h;
}

// ---------------------------------------------------------------------------
// aux_all: Wo cvt (4,194,304 f4) + rope_q (262,144) + rope_k (65,536) +
// cache_conv (1,048,576). Total 5,570,560 items = 21760 x 256.
// ---------------------------------------------------------------------------
__global__ void aux_all(const float* __restrict__ Wo, f16* __restrict__ w16,
                        f16* __restrict__ q16, const f16* __restrict__ kraw,
                        const float* __restrict__ cosp, const float* __restrict__ sinp,
                        f16* __restrict__ ck, const float* __restrict__ kvp,
                        const int* __restrict__ layer, f16* __restrict__ cv)
{
    int i = blockIdx.x * 256 + threadIdx.x;
    if (i < 4194304) {
        // ---- Wo fp32 -> fp16 ----
        f32x4 v = *(const f32x4*)(Wo + (size_t)i * 4);
        f16x4 h;
#pragma unroll
        for (int j = 0; j < 4; j++) h[j] = (f16)v[j];
        *(f16x4*)(w16 + (size_t)i * 4) = h;
    } else if (i < 4456448) {
        // ---- RoPE q in place (scale*log2e folded) ----
        int ii = i - 4194304;
        int gd = ii & 7, hh = (ii >> 3) & 31, s = ii >> 8;
        size_t b1 = (size_t)s * 4096 + hh * 128 + gd * 8;
        f16x8 x1 = *(f16x8*)(q16 + b1);
        f16x8 x2 = *(f16x8*)(q16 + b1 + 64);
        const float* c1 = cosp + s * 128 + gd * 8;
        const float* s1 = sinp + s * 128 + gd * 8;
        f16x8 o1, o2;
#pragma unroll
        for (int j = 0; j < 8; j++) {
            float a = (float)x1[j], b = (float)x2[j];
            o1[j] = (f16)((a * c1[j] - b * s1[j]) * QK_SCALE_LOG2);
            o2[j] = (f16)((b * c1[j + 64] + a * s1[j + 64]) * QK_SCALE_LOG2);
        }
        *(f16x8*)(q16 + b1) = o1;
        *(f16x8*)(q16 + b1 + 64) = o2;
    } else if (i < 4521984) {
        // ---- RoPE k -> cache at l = 2048+s ----
        int ii = i - 4456448;
        int gd = ii & 7, kvh = (ii >> 3) & 7, s = ii >> 6;
        size_t b1 = (size_t)s * 1024 + kvh * 128 + gd * 8;
        f16x8 x1 = *(const f16x8*)(kraw + b1);
        f16x8 x2 = *(const f16x8*)(kraw + b1 + 64);
        const float* c1 = cosp + s * 128 + gd * 8;
        const float* s1 = sinp + s * 128 + gd * 8;
        f16x8 o1, o2;
#pragma unroll
        for (int j = 0; j < 8; j++) {
            float a = (float)x1[j], b = (float)x2[j];
            o1[j] = (f16)(a * c1[j] - b * s1[j]);
            o2[j] = (f16)(b * c1[j + 64] + a * s1[j + 64]);
        }
        size_t dst = ((size_t)kvh * LCTX + PASTN + s) * 128 + gd * 8;
        *(f16x8*)(ck + dst) = o1;
        *(f16x8*)(ck + dst + 64) = o2;
    } else {
        // ---- cached kv (l<2048) fp32 -> ck / cv fp16 ----
        int i4 = i - 4521984;
        int half = i4 >> 19;
        int e = (i4 & 524287) * 4;
        int hh = e >> 18, rem = e & 262143, l = rem >> 7, d = rem & 127;
        int blk = l >> 4, rr = l & 15;
        size_t src = (((size_t)(layer[0] * 2 + half) * 256 + blk) * 8 + hh) * 2048
                   + (size_t)rr * 128 + d;
        f32x4 x = *(const f32x4*)(kvp + src);
        f16x4 h;
#pragma unroll
        for (int j = 0; j < 4; j++) h[j] = (f16)x[j];
        size_t dst = ((size_t)hh * LCTX + l) * 128 + d;
        *(f16x4*)((half ? cv : ck) + dst) = h;
    }
}

// ---------------------------------------------------------------------------
// GEMM: C[M,N] = A[M,K] @ B[N,K]^T, both fp16 row-major. (m97-style)
// ---------------------------------------------------------------------------
template <int EPI>
__global__ __launch_bounds__(256, 3) void gemm_f16(
    const f16* __restrict__ A, const f16* __restrict__ B,
    float* __restrict__ Cf, f16* __restrict__ Cq, f16* __restrict__ Ck,
    f16* __restrict__ Cv, int M, int N, int K)
{
    __shared__ f16 As[128 * 64];
    __shared__ f16 Bs[128 * 64];

    const int t = threadIdx.x, lane = t & 63, w = t >> 6;
    const int wm = w >> 1, wn = w & 1;
    const int l16 = lane & 15, g16 = lane >> 4;
    const int m0 = blockIdx.y * 128, n0 = blockIdx.x * 128;

    const int srow = lane >> 3;
    const int sgr  = (lane & 7) ^ srow;

    const size_t aoff = (size_t)(m0 + w * 32 + srow) * K + sgr * 8;
    const size_t boff = (size_t)(n0 + w * 32 + srow) * K + sgr * 8;

    f32x4 acc[4][4];
#pragma unroll
    for (int i = 0; i < 4; i++)
#pragma unroll
        for (int j = 0; j < 4; j++) acc[i][j] = (f32x4){0.f, 0.f, 0.f, 0.f};

    for (int k0 = 0; k0 < K; k0 += 64) {
#pragma unroll
        for (int j = 0; j < 4; j++) {
            gl_lds16(A + aoff + (size_t)j * 8 * K + k0, (void*)(As + (w * 32 + j * 8) * 64));
            gl_lds16(B + boff + (size_t)j * 8 * K + k0, (void*)(Bs + (w * 32 + j * 8) * 64));
        }
        __syncthreads();

#pragma unroll
        for (int ks = 0; ks < 2; ks++) {
            f16x8 af[4], bfr[4];
#pragma unroll
            for (int mi = 0; mi < 4; mi++) {
                int r = wm * 64 + mi * 16 + l16;
                int g = ks * 4 + g16;
                af[mi] = *(const f16x8*)&As[r * 64 + ((g ^ (r & 7)) << 3)];
            }
#pragma unroll
            for (int ni = 0; ni < 4; ni++) {
                int r = wn * 64 + ni * 16 + l16;
                int g = ks * 4 + g16;
                bfr[ni] = *(const f16x8*)&Bs[r * 64 + ((g ^ (r & 7)) << 3)];
            }
#pragma unroll
            for (int ni = 0; ni < 4; ni++)
#pragma unroll
                for (int mi = 0; mi < 4; mi++)
                    acc[mi][ni] = mfma16(af[mi], bfr[ni], acc[mi][ni]);
        }
        __syncthreads();
    }

#pragma unroll
    for (int mi = 0; mi < 4; mi++)
#pragma unroll
        for (int ni = 0; ni < 4; ni++)
#pragma unroll
            for (int r = 0; r < 4; r++) {
                int row = m0 + wm * 64 + mi * 16 + (g16 << 2) + r;
                int col = n0 + wn * 64 + ni * 16 + l16;
                float val = acc[mi][ni][r];
                if (EPI == 0) {
                    if (col < 4096) {
                        Cq[(size_t)row * 4096 + col] = (f16)val;
                    } else if (col < 5120) {
                        Ck[(size_t)row * 1024 + (col - 4096)] = (f16)val;
                    } else {
                        int c = col - 5120;
                        int hh = c >> 7, d = c & 127;
                        Cv[((size_t)hh * LCTX + PASTN + row) * 128 + d] = (f16)val;
                    }
                } else {
                    Cf[(size_t)row * N + col] = val;
                }
            }
}

// ---------------------------------------------------------------------------
// Flash attention: swapped QK^T, x16-MFMA PV, K global->reg pipelined.
// Grid: 512 blocks 1-D; balanced causal remap (b and b+256 sum to 81 tiles).
// K fragments kf[ni][kk] (64 VGPR) loaded straight from global (L2-hot);
// single-buffered: kf is dead after QK(t), so kf <- K(t+1) issues right
// after QK(t); compiler's waitcnt-before-use covers arrival. Only V is
// LDS-staged (dbuf, tr_b16 region layout) -> DS pipe carries tr-reads only.
// ---------------------------------------------------------------------------
__global__ __launch_bounds__(256, 2) void attn_f16(
    const f16* __restrict__ Q, const f16* __restrict__ Kc,
    const f16* __restrict__ Vc, f16* __restrict__ Og)
{
    const int b = blockIdx.x;
    const int idx = b & 255;
    const int h = idx & 31;
    const int jt = idx >> 5;
    const int tile = (b >> 8) ? (15 - jt) : jt;
    const int s0 = tile * 64;
    const int kvh = h >> 2;
    const int t = threadIdx.x, lane = t & 63, w = t >> 6;
    const int l16 = lane & 15, g16 = lane >> 4;

    __shared__ f16 Vs[2][64 * 128];   // x16-tr region layout

    // Q fragments (B-operand of swapped QK^T); rows = s0 + w*16 + l16
    f16x8 qf[4];
    {
        size_t base = (size_t)(s0 + w * 16 + l16) * 4096 + h * 128;
#pragma unroll
        for (int kk = 0; kk < 4; kk++)
            qf[kk] = *(const f16x8*)(Q + base + kk * 32 + g16 * 8);
    }

    f32x4 of[8];
#pragma unroll
    for (int cf = 0; cf < 8; cf++) of[cf] = (f32x4){0.f, 0.f, 0.f, 0.f};
    float mr = -3.0e38f, lr = 0.f;    // per-lane; lr holds a PARTIAL sum

    const f16* Kb = Kc + (size_t)kvh * LCTX * 128;
    const f16* Vb = Vc + (size_t)kvh * LCTX * 128;
    const int nt = (PASTN + s0 + 64) >> 6;

    // per-lane K base: row l16, col granule g16*8 (A-frag of swapped QK^T)
    const f16* kaddr = Kb + (size_t)l16 * 128 + g16 * 8;
    f16x8 kf[4][4];

    // V staging lane map for the x16 region layout
    const int vrow = ((lane >> 5) << 4) + (((lane >> 3) & 3) << 2) + ((lane >> 1) & 3);
    const int vch  = (lane & 1) << 3;

    const uint32_t vs0 = lds_lo(Vs[0]) + lane * 8;
    const uint32_t vs1 = lds_lo(Vs[1]) + lane * 8;

#define STAGE_V(l0, buf)                                                      \
    {                                                                         \
        _Pragma("unroll")                                                     \
        for (int q = 0; q < 4; q++) {                                         \
            gl_lds16(Vb + (size_t)((l0) + (q & 1) * 32 + vrow) * 128          \
                        + (w * 2 + (q >> 1)) * 16 + vch,                      \
                     (void*)(Vs[buf] + (w * 4 + q) * 512));                   \
        }                                                                     \
    }

#define LOADK(l0)                                                             \
    {                                                                         \
        _Pragma("unroll")                                                     \
        for (int ni = 0; ni < 4; ni++) {                                      \
            _Pragma("unroll")                                                 \
            for (int kk = 0; kk < 4; kk++)                                    \
                kf[ni][kk] = *(const f16x8*)(kaddr                            \
                    + (size_t)((l0) + ni * 16) * 128 + kk * 32);              \
        }                                                                     \
    }

    STAGE_V(0, 0);
    LOADK(0);
    __syncthreads();

    for (int it = 0; it < nt; ++it) {
        const int l0 = it << 6;
        const int cur = it & 1;

        // prefetch next V tile into the other LDS buffer
        if (it + 1 < nt) STAGE_V(l0 + 64, cur ^ 1);

        // ---- S^T = K Q^T  (D[kv=(g16<<2)+r + 16ni][q=l16]) ----
        f32x4 sf[4];
#pragma unroll
        for (int ni = 0; ni < 4; ni++) sf[ni] = (f32x4){0.f, 0.f, 0.f, 0.f};
        __builtin_amdgcn_s_setprio(1);
#pragma unroll
        for (int ni = 0; ni < 4; ni++)
#pragma unroll
            for (int kk = 0; kk < 4; kk++)
                sf[ni] = mfma16(kf[ni][kk], qf[kk], sf[ni]);
        __builtin_amdgcn_s_setprio(0);

        // kf regs dead now: issue next tile's K loads (latency hides under
        // softmax+PV; waitcnt inserted by compiler before next use)
        if (it + 1 < nt) LOADK(l0 + 64);

        const int qrow = s0 + w * 16 + l16;       // this lane's q-row
        const bool needmask = (l0 + 63 > PASTN + s0);
        if (needmask) {
#pragma unroll
            for (int ni = 0; ni < 4; ni++)
#pragma unroll
                for (int r = 0; r < 4; r++) {
                    int col = l0 + ni * 16 + (g16 << 2) + r;
                    if (col > PASTN + qrow) sf[ni][r] = -3.0e38f;
                }
        }

        // ---- lane-local softmax (log2 domain), deferred sum-reduce ----
        float mx;
        {
            f32x4 m4 = sf[0];
#pragma unroll
            for (int ni = 1; ni < 4; ni++) {
                m4[0] = fmaxf(m4[0], sf[ni][0]); m4[1] = fmaxf(m4[1], sf[ni][1]);
                m4[2] = fmaxf(m4[2], sf[ni][2]); m4[3] = fmaxf(m4[3], sf[ni][3]);
            }
            mx = fmaxf(fmaxf(m4[0], m4[1]), fmaxf(m4[2], m4[3]));
        }
        mx = fmaxf(mx, __shfl_xor(mx, 16));
        mx = fmaxf(mx, __shfl_xor(mx, 32));
        if (__any(mx > mr + RESC_THR)) {
            float mnew = fmaxf(mr, mx);
            float corr = exp2f(mr - mnew);    // row-uniform
            mr = mnew;
            lr *= corr;
            float cr[4];
#pragma unroll
            for (int r = 0; r < 4; r++) cr[r] = __shfl(corr, (g16 << 2) + r);
#pragma unroll
            for (int cf = 0; cf < 8; cf++)
#pragma unroll
                for (int r = 0; r < 4; r++) of[cf][r] *= cr[r];
        }
#pragma unroll
        for (int ni = 0; ni < 4; ni++)
#pragma unroll
            for (int r = 0; r < 4; r++) {
                float p = exp2f(sf[ni][r] - mr);
                sf[ni][r] = p;
                lr += p;                      // lane-partial; reduced after loop
            }

        // ---- P fragments directly from sf (x16 A-frag: k = 4*g16 + r) ----
        f16x4 pa[4];
#pragma unroll
        for (int ni = 0; ni < 4; ni++) {
            pa[ni][0] = (f16)sf[ni][0]; pa[ni][1] = (f16)sf[ni][1];
            pa[ni][2] = (f16)sf[ni][2]; pa[ni][3] = (f16)sf[ni][3];
        }

        // ---- O += P @ V  (32 tr-reads feeding 32 x16 MFMAs, counted waits) --
        {
            const uint32_t va = cur ? vs1 : vs0;
            f16x4 r0,r1,r2,r3,r4,r5,r6,r7,r8,r9,r10,r11,r12,r13,r14,r15,
                  r16,r17,r18,r19,r20,r21,r22,r23,r24,r25,r26,r27,r28,r29,r30,r31;
            __builtin_amdgcn_s_setprio(1);
            TRRD(r0,va,0);      TRRD(r1,va,512);    TRRD(r2,va,1024);   TRRD(r3,va,1536);
            TRRD(r4,va,2048);   TRRD(r5,va,2560);   TRRD(r6,va,3072);   TRRD(r7,va,3584);
            TRRD(r8,va,4096);   TRRD(r9,va,4608);   TRRD(r10,va,5120);  TRRD(r11,va,5632);
#define X16(cf, ni, reg) of[cf] = mfma16k16(pa[ni], reg, of[cf]);
            WAITL(8);
            X16(0,0,r0)  X16(0,1,r1)  X16(0,2,r2)  X16(0,3,r3)
            TRRD(r12,va,6144);  TRRD(r13,va,6656);  TRRD(r14,va,7168);  TRRD(r15,va,7680);
            WAITL(8);
            X16(1,0,r4)  X16(1,1,r5)  X16(1,2,r6)  X16(1,3,r7)
            TRRD(r16,va,8192);  TRRD(r17,va,8704);  TRRD(r18,va,9216);  TRRD(r19,va,9728);
            WAITL(8);
            X16(2,0,r8)  X16(2,1,r9)  X16(2,2,r10) X16(2,3,r11)
            TRRD(r20,va,10240); TRRD(r21,va,10752); TRRD(r22,va,11264); TRRD(r23,va,11776);
            WAITL(8);
            X16(3,0,r12) X16(3,1,r13) X16(3,2,r14) X16(3,3,r15)
            TRRD(r24,va,12288); TRRD(r25,va,12800); TRRD(r26,va,13312); TRRD(r27,va,13824);
            WAITL(8);
            X16(4,0,r16) X16(4,1,r17) X16(4,2,r18) X16(4,3,r19)
            TRRD(r28,va,14336); TRRD(r29,va,14848); TRRD(r30,va,15360); TRRD(r31,va,15872);
            WAITL(8);
            X16(5,0,r20) X16(5,1,r21) X16(5,2,r22) X16(5,3,r23)
            WAITL(4);
            X16(6,0,r24) X16(6,1,r25) X16(6,2,r26) X16(6,3,r27)
            WAITL(0);
            X16(7,0,r28) X16(7,1,r29) X16(7,2,r30) X16(7,3,r31)
#undef X16
            __builtin_amdgcn_s_setprio(0);
        }
        __syncthreads();   // V(t+1) landed (vmcnt drained at barrier)
    }

    // ---- final sum-reduce, normalize + write o (fp16) ----
    lr += __shfl_xor(lr, 16);
    lr += __shfl_xor(lr, 32);
    float lrr[4];
#pragma unroll
    for (int r = 0; r < 4; r++) lrr[r] = __shfl(lr, (g16 << 2) + r);
#pragma unroll
    for (int cf = 0; cf < 8; cf++)
#pragma unroll
        for (int r = 0; r < 4; r++) {
            int srow = s0 + w * 16 + (g16 << 2) + r;
            int d = cf * 16 + l16;
            Og[(size_t)srow * 4096 + (size_t)h * 128 + d] = (f16)(of[cf][r] / lrr[r]);
        }
#undef STAGE_V
#undef LOADK
}

// ---------------------------------------------------------------------------
// launcher
// ---------------------------------------------------------------------------
extern "C" void kernel_launch(void* const* d_in, const int* in_sizes, int n_in,
                              void* d_out, int out_size, void* d_ws, size_t ws_size,
                              hipStream_t stream)
{
    const float* hidden = (const float*)d_in[0];
    const float* kvp    = (const float*)d_in[1];
    const float* cosp   = (const float*)d_in[7];
    const float* sinp   = (const float*)d_in[8];
    const float* Wq     = (const float*)d_in[9];
    const float* Wk     = (const float*)d_in[10];
    const float* Wv     = (const float*)d_in[11];
    const float* Wo     = (const float*)d_in[12];
    const int*   layer  = (const int*)d_in[13];

    char* ws = (char*)d_ws;
    f16* w16  = (f16*)ws;                   // 50,331,648 B (Wqkv; later reused for Wo)
    f16* h16  = (f16*)(ws + 50331648);      //  8,388,608
    f16* ck   = (f16*)(ws + 58720256);      //  6,291,456
    f16* cv   = (f16*)(ws + 65011712);      //  6,291,456
    f16* obuf = (f16*)(ws + 71303168);      //  8,388,608

    f16* q16  = (f16*)d_out;                      // 8 MB scratch inside d_out
    f16* kraw = (f16*)((char*)d_out + 8388608);   // 2 MB

    // 1) fp32 -> fp16 conversions (hidden + Wq + Wk + Wv, one launch)
    cvt_all<<<28672, 256, 0, stream>>>(hidden, Wq, Wk, Wv, h16, w16);

    // 2) fused QKV projection
    gemm_f16<0><<<dim3(48, 8), 256, 0, stream>>>(
        h16, w16, nullptr, q16, kraw, cv, 1024, 6144, 4096);

    // 3) Wo cvt + RoPE q/k + cached-KV convert (one launch)
    aux_all<<<21760, 256, 0, stream>>>(Wo, w16, q16, kraw, cosp, sinp,
                                       ck, kvp, layer, cv);

    // 4) flash attention (balanced 1-D grid, K global->reg, V dbuf LDS)
    attn_f16<<<dim3(512), 256, 0, stream>>>(q16, ck, cv, obuf);

    // 5) output projection -> d_out fp32
    gemm_f16<1><<<dim3(32, 8), 256, 0, stream>>>(
        obuf, w16, (float*)d_out, nullptr, nullptr, nullptr, 1024, 4096, 4096);
}

// Round 8
// 275.090 us; speedup vs baseline: 1.3313x; 1.3313x over previous
//
#include <hip/hip_runtime.h>
#include <cstdint>
#include <cstddef>

// ---------------------------------------------------------------------------
// L4maAttention, fp16 pipeline (round 8):
//   cvt_all -> QKV GEMM (split-K=2, fp16 partials, XCD-swizzled) ->
//   aux_all (Wo cvt + sum-halves + RoPE q/k + cache convert + new-V scatter)
//   -> flash attention (round-6 structure: LDS K dbuf + V tr_b16 dbuf,
//   swapped QK^T lane-local softmax, x16-MFMA PV) ->
//   O-proj GEMM (split-K=2) -> sum2 -> d_out fp32.
// ---------------------------------------------------------------------------

typedef _Float16 f16;
typedef f16 f16x8 __attribute__((ext_vector_type(8)));
typedef f16 f16x4 __attribute__((ext_vector_type(4)));
typedef float f32x4 __attribute__((ext_vector_type(4)));

#define HIDN 4096
#define LCTX 3072
#define PASTN 2048
// 1/sqrt(128) * log2(e): QK^T computed in log2 domain (exp2-based softmax)
#define QK_SCALE_LOG2 0.12753102734366334f
#define RESC_THR 11.54f   /* defer-max threshold, log2 units (~8 nats) */

__device__ __forceinline__ f32x4 mfma16(f16x8 a, f16x8 b, f32x4 c) {
    return __builtin_amdgcn_mfma_f32_16x16x32_f16(a, b, c, 0, 0, 0);
}
__device__ __forceinline__ f32x4 mfma16k16(f16x4 a, f16x4 b, f32x4 c) {
    return __builtin_amdgcn_mfma_f32_16x16x16f16(a, b, c, 0, 0, 0);
}

__device__ __forceinline__ void gl_lds16(const void* g, void* l) {
    auto gp = (const __attribute__((address_space(1))) unsigned int*)(uintptr_t)g;
    auto lp = (__attribute__((address_space(3))) unsigned int*)(uintptr_t)l;
    __builtin_amdgcn_global_load_lds(gp, lp, 16, 0, 0);
}

__device__ __forceinline__ uint32_t lds_lo(const void* p) {
    return (uint32_t)(uintptr_t)p;
}

#define TRRD(dst, va, OFF) \
    asm volatile("ds_read_b64_tr_b16 %0, %1 offset:" #OFF : "=v"(dst) : "v"(va))
#define WAITL(N) \
    asm volatile("s_waitcnt lgkmcnt(" #N ")" ::: "memory"); \
    __builtin_amdgcn_sched_barrier(0)

// ---------------------------------------------------------------------------
// fused fp32 -> fp16 conversions: hidden (1M f4), Wq (4M), Wk (1M), Wv (1M)
// ---------------------------------------------------------------------------
__global__ void cvt_all(const float* __restrict__ hidden, const float* __restrict__ Wq,
                        const float* __restrict__ Wk, const float* __restrict__ Wv,
                        f16* __restrict__ h16, f16* __restrict__ w16)
{
    int i = blockIdx.x * 256 + threadIdx.x;
    const float* src; f16* dst; int off;
    if (i < 1048576)      { src = hidden; dst = h16; off = i; }
    else if (i < 5242880) { src = Wq; dst = w16; off = i - 1048576; }
    else if (i < 6291456) { src = Wk; dst = w16 + (size_t)4096 * 4096; off = i - 5242880; }
    else                  { src = Wv; dst = w16 + (size_t)5120 * 4096; off = i - 6291456; }
    f32x4 v = *(const f32x4*)(src + (size_t)off * 4);
    f16x4 h;
#pragma unroll
    for (int j = 0; j < 4; j++) h[j] = (f16)v[j];
    *(f16x4*)(dst + (size_t)off * 4) = h;
}

// ---------------------------------------------------------------------------
// GEMM: C = A[M,K] @ B[N,K]^T, fp16, 128x128 tile, BK=64, split-K=2 (z-dim),
// bijective XCD swizzle on the (x,y)-flattened index (nblk % 8 == 0).
// EPI 0 (QKV): col<4096 -> Cq half, <5120 -> Ck half, else -> Cv half
//              (all linear row-major fp16 partials, + z*half_elems).
// EPI 1 (o-proj): fp16 partial to (z ? C1 : C0).
// ---------------------------------------------------------------------------
template <int EPI>
__global__ __launch_bounds__(256, 3) void gemm_f16(
    const f16* __restrict__ A, const f16* __restrict__ B,
    f16* __restrict__ C0, f16* __restrict__ C1, f16* __restrict__ C2,
    int M, int N, int K)
{
    __shared__ f16 As[128 * 64];
    __shared__ f16 Bs[128 * 64];

    const int t = threadIdx.x, lane = t & 63, w = t >> 6;
    const int wm = w >> 1, wn = w & 1;
    const int l16 = lane & 15, g16 = lane >> 4;

    // XCD-bijective swizzle of the flattened (x,y) block index
    const int nblk = gridDim.x * gridDim.y;
    const int lin  = blockIdx.y * gridDim.x + blockIdx.x;
    const int cpx  = nblk >> 3;
    const int swz  = (lin & 7) * cpx + (lin >> 3);
    const int m0 = (swz / gridDim.x) * 128, n0 = (swz % gridDim.x) * 128;

    const int z = blockIdx.z;
    const int khalf = K >> 1;
    const int kbeg = z * khalf, kend = kbeg + khalf;

    const int srow = lane >> 3;
    const int sgr  = (lane & 7) ^ srow;

    const size_t aoff = (size_t)(m0 + w * 32 + srow) * K + sgr * 8;
    const size_t boff = (size_t)(n0 + w * 32 + srow) * K + sgr * 8;

    f32x4 acc[4][4];
#pragma unroll
    for (int i = 0; i < 4; i++)
#pragma unroll
        for (int j = 0; j < 4; j++) acc[i][j] = (f32x4){0.f, 0.f, 0.f, 0.f};

    for (int k0 = kbeg; k0 < kend; k0 += 64) {
#pragma unroll
        for (int j = 0; j < 4; j++) {
            gl_lds16(A + aoff + (size_t)j * 8 * K + k0, (void*)(As + (w * 32 + j * 8) * 64));
            gl_lds16(B + boff + (size_t)j * 8 * K + k0, (void*)(Bs + (w * 32 + j * 8) * 64));
        }
        __syncthreads();

#pragma unroll
        for (int ks = 0; ks < 2; ks++) {
            f16x8 af[4], bfr[4];
#pragma unroll
            for (int mi = 0; mi < 4; mi++) {
                int r = wm * 64 + mi * 16 + l16;
                int g = ks * 4 + g16;
                af[mi] = *(const f16x8*)&As[r * 64 + ((g ^ (r & 7)) << 3)];
            }
#pragma unroll
            for (int ni = 0; ni < 4; ni++) {
                int r = wn * 64 + ni * 16 + l16;
                int g = ks * 4 + g16;
                bfr[ni] = *(const f16x8*)&Bs[r * 64 + ((g ^ (r & 7)) << 3)];
            }
#pragma unroll
            for (int ni = 0; ni < 4; ni++)
#pragma unroll
                for (int mi = 0; mi < 4; mi++)
                    acc[mi][ni] = mfma16(af[mi], bfr[ni], acc[mi][ni]);
        }
        __syncthreads();
    }

#pragma unroll
    for (int mi = 0; mi < 4; mi++)
#pragma unroll
        for (int ni = 0; ni < 4; ni++)
#pragma unroll
            for (int r = 0; r < 4; r++) {
                int row = m0 + wm * 64 + mi * 16 + (g16 << 2) + r;
                int col = n0 + wn * 64 + ni * 16 + l16;
                f16 val = (f16)acc[mi][ni][r];
                if (EPI == 0) {
                    if (col < 4096) {
                        C0[(size_t)z * 4194304 + (size_t)row * 4096 + col] = val;
                    } else if (col < 5120) {
                        C1[(size_t)z * 1048576 + (size_t)row * 1024 + (col - 4096)] = val;
                    } else {
                        C2[(size_t)z * 1048576 + (size_t)row * 1024 + (col - 5120)] = val;
                    }
                } else {
                    (z ? C1 : C0)[(size_t)row * 4096 + col] = val;
                }
            }
}

// ---------------------------------------------------------------------------
// aux_all: Wo cvt (4,194,304 f4) + rope_q sum-halves in place (262,144) +
// rope_k sum-halves -> ck (65,536) + cached-KV convert (1,048,576) +
// new-V sum-halves -> cv scatter (131,072). Total 5,701,632 = 22272 x 256.
// ---------------------------------------------------------------------------
__global__ void aux_all(const float* __restrict__ Wo, f16* __restrict__ w16,
                        f16* __restrict__ qh, const f16* __restrict__ kh,
                        const f16* __restrict__ vh,
                        const float* __restrict__ cosp, const float* __restrict__ sinp,
                        f16* __restrict__ ck, const float* __restrict__ kvp,
                        const int* __restrict__ layer, f16* __restrict__ cv)
{
    int i = blockIdx.x * 256 + threadIdx.x;
    if (i < 4194304) {
        // ---- Wo fp32 -> fp16 ----
        f32x4 v = *(const f32x4*)(Wo + (size_t)i * 4);
        f16x4 h;
#pragma unroll
        for (int j = 0; j < 4; j++) h[j] = (f16)v[j];
        *(f16x4*)(w16 + (size_t)i * 4) = h;
    } else if (i < 4456448) {
        // ---- RoPE q: sum split-K halves, rope, write in place (half0) ----
        int ii = i - 4194304;
        int gd = ii & 7, hh = (ii >> 3) & 31, s = ii >> 8;
        size_t b1 = (size_t)s * 4096 + hh * 128 + gd * 8;
        f16x8 xa0 = *(const f16x8*)(qh + b1);
        f16x8 xa1 = *(const f16x8*)(qh + 4194304 + b1);
        f16x8 xb0 = *(const f16x8*)(qh + b1 + 64);
        f16x8 xb1 = *(const f16x8*)(qh + 4194304 + b1 + 64);
        const float* c1 = cosp + s * 128 + gd * 8;
        const float* s1 = sinp + s * 128 + gd * 8;
        f16x8 o1, o2;
#pragma unroll
        for (int j = 0; j < 8; j++) {
            float a = (float)xa0[j] + (float)xa1[j];
            float b = (float)xb0[j] + (float)xb1[j];
            o1[j] = (f16)((a * c1[j] - b * s1[j]) * QK_SCALE_LOG2);
            o2[j] = (f16)((b * c1[j + 64] + a * s1[j + 64]) * QK_SCALE_LOG2);
        }
        *(f16x8*)(qh + b1) = o1;
        *(f16x8*)(qh + b1 + 64) = o2;
    } else if (i < 4521984) {
        // ---- RoPE k: sum halves -> cache at l = 2048+s ----
        int ii = i - 4456448;
        int gd = ii & 7, kvh = (ii >> 3) & 7, s = ii >> 6;
        size_t b1 = (size_t)s * 1024 + kvh * 128 + gd * 8;
        f16x8 xa0 = *(const f16x8*)(kh + b1);
        f16x8 xa1 = *(const f16x8*)(kh + 1048576 + b1);
        f16x8 xb0 = *(const f16x8*)(kh + b1 + 64);
        f16x8 xb1 = *(const f16x8*)(kh + 1048576 + b1 + 64);
        const float* c1 = cosp + s * 128 + gd * 8;
        const float* s1 = sinp + s * 128 + gd * 8;
        f16x8 o1, o2;
#pragma unroll
        for (int j = 0; j < 8; j++) {
            float a = (float)xa0[j] + (float)xa1[j];
            float b = (float)xb0[j] + (float)xb1[j];
            o1[j] = (f16)(a * c1[j] - b * s1[j]);
            o2[j] = (f16)(b * c1[j + 64] + a * s1[j + 64]);
        }
        size_t dst = ((size_t)kvh * LCTX + PASTN + s) * 128 + gd * 8;
        *(f16x8*)(ck + dst) = o1;
        *(f16x8*)(ck + dst + 64) = o2;
    } else if (i < 5570560) {
        // ---- cached kv (l<2048) fp32 -> ck / cv fp16 ----
        int i4 = i - 4521984;
        int half = i4 >> 19;
        int e = (i4 & 524287) * 4;
        int hh = e >> 18, rem = e & 262143, l = rem >> 7, d = rem & 127;
        int blk = l >> 4, rr = l & 15;
        size_t src = (((size_t)(layer[0] * 2 + half) * 256 + blk) * 8 + hh) * 2048
                   + (size_t)rr * 128 + d;
        f32x4 x = *(const f32x4*)(kvp + src);
        f16x4 h;
#pragma unroll
        for (int j = 0; j < 4; j++) h[j] = (f16)x[j];
        size_t dst = ((size_t)hh * LCTX + l) * 128 + d;
        *(f16x4*)((half ? cv : ck) + dst) = h;
    } else {
        // ---- new V: sum halves -> cv at l = 2048+row ----
        int ii = i - 5570560;                 // 0..131071, 8 f16 each
        int e = ii * 8;
        int row = e >> 10, c = e & 1023;
        int hh = c >> 7, d = c & 127;
        f16x8 v0 = *(const f16x8*)(vh + (size_t)row * 1024 + c);
        f16x8 v1 = *(const f16x8*)(vh + 1048576 + (size_t)row * 1024 + c);
        f16x8 o;
#pragma unroll
        for (int j = 0; j < 8; j++) o[j] = (f16)((float)v0[j] + (float)v1[j]);
        *(f16x8*)(cv + ((size_t)hh * LCTX + PASTN + row) * 128 + d) = o;
    }
}

// ---------------------------------------------------------------------------
// sum2: d_out fp32 = oh0 + oh1 (o-proj split-K halves, fp16)
// ---------------------------------------------------------------------------
__global__ void sum2(const f16* __restrict__ oh0, const f16* __restrict__ oh1,
                     float* __restrict__ out)
{
    int i = blockIdx.x * 256 + threadIdx.x;   // 524288 threads x 8 elems
    size_t e = (size_t)i * 8;
    f16x8 a = *(const f16x8*)(oh0 + e);
    f16x8 b = *(const f16x8*)(oh1 + e);
    f32x4 lo, hi;
#pragma unroll
    for (int j = 0; j < 4; j++) lo[j] = (float)a[j] + (float)b[j];
#pragma unroll
    for (int j = 0; j < 4; j++) hi[j] = (float)a[j + 4] + (float)b[j + 4];
    *(f32x4*)(out + e) = lo;
    *(f32x4*)(out + e + 4) = hi;
}

// ---------------------------------------------------------------------------
// Flash attention (round-6 structure): 2-phase dbuf, swapped QK^T, x16 PV.
// Grid: 512 blocks 1-D; balanced causal remap (b and b+256 sum to 81 tiles).
// ---------------------------------------------------------------------------
__global__ __launch_bounds__(256, 2) void attn_f16(
    const f16* __restrict__ Q, const f16* __restrict__ Kc,
    const f16* __restrict__ Vc, f16* __restrict__ Og)
{
    const int b = blockIdx.x;
    const int idx = b & 255;
    const int h = idx & 31;
    const int jt = idx >> 5;
    const int tile = (b >> 8) ? (15 - jt) : jt;
    const int s0 = tile * 64;
    const int kvh = h >> 2;
    const int t = threadIdx.x, lane = t & 63, w = t >> 6;
    const int l16 = lane & 15, g16 = lane >> 4;

    __shared__ f16 Ks[2][64 * 128];
    __shared__ f16 Vs[2][64 * 128];   // x16-tr region layout

    f16x8 qf[4];
    {
        size_t base = (size_t)(s0 + w * 16 + l16) * 4096 + h * 128;
#pragma unroll
        for (int kk = 0; kk < 4; kk++)
            qf[kk] = *(const f16x8*)(Q + base + kk * 32 + g16 * 8);
    }

    f32x4 of[8];
#pragma unroll
    for (int cf = 0; cf < 8; cf++) of[cf] = (f32x4){0.f, 0.f, 0.f, 0.f};
    float mr = -3.0e38f, lr = 0.f;

    const f16* Kb = Kc + (size_t)kvh * LCTX * 128;
    const f16* Vb = Vc + (size_t)kvh * LCTX * 128;
    const int nt = (PASTN + s0 + 64) >> 6;

    const int krow = lane >> 4;
    const int kp   = lane & 15;
    const int vrow = ((lane >> 5) << 4) + (((lane >> 3) & 3) << 2) + ((lane >> 1) & 3);
    const int vch  = (lane & 1) << 3;

    const uint32_t vs0 = lds_lo(Vs[0]) + lane * 8;
    const uint32_t vs1 = lds_lo(Vs[1]) + lane * 8;

#define STAGE_KV(l0, buf)                                                     \
    {                                                                         \
        _Pragma("unroll")                                                     \
        for (int j = 0; j < 4; j++) {                                         \
            int r7 = ((j & 1) << 2) + krow;                                   \
            int sg = kp ^ r7;                                                 \
            gl_lds16(Kb + (size_t)((l0) + w * 16 + j * 4 + krow) * 128 + sg * 8, \
                     (void*)(Ks[buf] + (w * 16 + j * 4) * 128));              \
        }                                                                     \
        _Pragma("unroll")                                                     \
        for (int q = 0; q < 4; q++) {                                         \
            gl_lds16(Vb + (size_t)((l0) + (q & 1) * 32 + vrow) * 128          \
                        + (w * 2 + (q >> 1)) * 16 + vch,                      \
                     (void*)(Vs[buf] + (w * 4 + q) * 512));                   \
        }                                                                     \
    }

    STAGE_KV(0, 0);
    __syncthreads();

    for (int it = 0; it < nt; ++it) {
        const int l0 = it << 6;
        const int cur = it & 1;

        if (it + 1 < nt) STAGE_KV(l0 + 64, cur ^ 1);

        // ---- S^T = K Q^T ----
        f32x4 sf[4];
#pragma unroll
        for (int ni = 0; ni < 4; ni++) sf[ni] = (f32x4){0.f, 0.f, 0.f, 0.f};
        __builtin_amdgcn_s_setprio(1);
#pragma unroll
        for (int ni = 0; ni < 4; ni++)
#pragma unroll
            for (int kk = 0; kk < 4; kk++) {
                int r = ni * 16 + l16;
                int g = kk * 4 + g16;
                f16x8 kh = *(const f16x8*)&Ks[cur][r * 128 + ((g ^ (r & 7)) << 3)];
                sf[ni] = mfma16(kh, qf[kk], sf[ni]);
            }
        __builtin_amdgcn_s_setprio(0);

        const int qrow = s0 + w * 16 + l16;
        const bool needmask = (l0 + 63 > PASTN + s0);
        if (needmask) {
#pragma unroll
            for (int ni = 0; ni < 4; ni++)
#pragma unroll
                for (int r = 0; r < 4; r++) {
                    int col = l0 + ni * 16 + (g16 << 2) + r;
                    if (col > PASTN + qrow) sf[ni][r] = -3.0e38f;
                }
        }

        // ---- lane-local softmax (log2 domain), deferred sum-reduce ----
        float mx;
        {
            f32x4 m4 = sf[0];
#pragma unroll
            for (int ni = 1; ni < 4; ni++) {
                m4[0] = fmaxf(m4[0], sf[ni][0]); m4[1] = fmaxf(m4[1], sf[ni][1]);
                m4[2] = fmaxf(m4[2], sf[ni][2]); m4[3] = fmaxf(m4[3], sf[ni][3]);
            }
            mx = fmaxf(fmaxf(m4[0], m4[1]), fmaxf(m4[2], m4[3]));
        }
        mx = fmaxf(mx, __shfl_xor(mx, 16));
        mx = fmaxf(mx, __shfl_xor(mx, 32));
        if (__any(mx > mr + RESC_THR)) {
            float mnew = fmaxf(mr, mx);
            float corr = exp2f(mr - mnew);
            mr = mnew;
            lr *= corr;
            float cr[4];
#pragma unroll
            for (int r = 0; r < 4; r++) cr[r] = __shfl(corr, (g16 << 2) + r);
#pragma unroll
            for (int cf = 0; cf < 8; cf++)
#pragma unroll
                for (int r = 0; r < 4; r++) of[cf][r] *= cr[r];
        }
#pragma unroll
        for (int ni = 0; ni < 4; ni++)
#pragma unroll
            for (int r = 0; r < 4; r++) {
                float p = exp2f(sf[ni][r] - mr);
                sf[ni][r] = p;
                lr += p;
            }

        // ---- P fragments directly from sf ----
        f16x4 pa[4];
#pragma unroll
        for (int ni = 0; ni < 4; ni++) {
            pa[ni][0] = (f16)sf[ni][0]; pa[ni][1] = (f16)sf[ni][1];
            pa[ni][2] = (f16)sf[ni][2]; pa[ni][3] = (f16)sf[ni][3];
        }

        // ---- O += P @ V  (32 tr-reads feeding 32 x16 MFMAs) ----
        {
            const uint32_t va = cur ? vs1 : vs0;
            f16x4 r0,r1,r2,r3,r4,r5,r6,r7,r8,r9,r10,r11,r12,r13,r14,r15,
                  r16,r17,r18,r19,r20,r21,r22,r23,r24,r25,r26,r27,r28,r29,r30,r31;
            __builtin_amdgcn_s_setprio(1);
            TRRD(r0,va,0);      TRRD(r1,va,512);    TRRD(r2,va,1024);   TRRD(r3,va,1536);
            TRRD(r4,va,2048);   TRRD(r5,va,2560);   TRRD(r6,va,3072);   TRRD(r7,va,3584);
            TRRD(r8,va,4096);   TRRD(r9,va,4608);   TRRD(r10,va,5120);  TRRD(r11,va,5632);
#define X16(cf, ni, reg) of[cf] = mfma16k16(pa[ni], reg, of[cf]);
            WAITL(8);
            X16(0,0,r0)  X16(0,1,r1)  X16(0,2,r2)  X16(0,3,r3)
            TRRD(r12,va,6144);  TRRD(r13,va,6656);  TRRD(r14,va,7168);  TRRD(r15,va,7680);
            WAITL(8);
            X16(1,0,r4)  X16(1,1,r5)  X16(1,2,r6)  X16(1,3,r7)
            TRRD(r16,va,8192);  TRRD(r17,va,8704);  TRRD(r18,va,9216);  TRRD(r19,va,9728);
            WAITL(8);
            X16(2,0,r8)  X16(2,1,r9)  X16(2,2,r10) X16(2,3,r11)
            TRRD(r20,va,10240); TRRD(r21,va,10752); TRRD(r22,va,11264); TRRD(r23,va,11776);
            WAITL(8);
            X16(3,0,r12) X16(3,1,r13) X16(3,2,r14) X16(3,3,r15)
            TRRD(r24,va,12288); TRRD(r25,va,12800); TRRD(r26,va,13312); TRRD(r27,va,13824);
            WAITL(8);
            X16(4,0,r16) X16(4,1,r17) X16(4,2,r18) X16(4,3,r19)
            TRRD(r28,va,14336); TRRD(r29,va,14848); TRRD(r30,va,15360); TRRD(r31,va,15872);
            WAITL(8);
            X16(5,0,r20) X16(5,1,r21) X16(5,2,r22) X16(5,3,r23)
            WAITL(4);
            X16(6,0,r24) X16(6,1,r25) X16(6,2,r26) X16(6,3,r27)
            WAITL(0);
            X16(7,0,r28) X16(7,1,r29) X16(7,2,r30) X16(7,3,r31)
#undef X16
            __builtin_amdgcn_s_setprio(0);
        }
        __syncthreads();
    }

    // ---- final sum-reduce, normalize + write o (fp16) ----
    lr += __shfl_xor(lr, 16);
    lr += __shfl_xor(lr, 32);
    float lrr[4];
#pragma unroll
    for (int r = 0; r < 4; r++) lrr[r] = __shfl(lr, (g16 << 2) + r);
#pragma unroll
    for (int cf = 0; cf < 8; cf++)
#pragma unroll
        for (int r = 0; r < 4; r++) {
            int srow = s0 + w * 16 + (g16 << 2) + r;
            int d = cf * 16 + l16;
            Og[(size_t)srow * 4096 + (size_t)h * 128 + d] = (f16)(of[cf][r] / lrr[r]);
        }
#undef STAGE_KV
}

// ---------------------------------------------------------------------------
// launcher
// ---------------------------------------------------------------------------
extern "C" void kernel_launch(void* const* d_in, const int* in_sizes, int n_in,
                              void* d_out, int out_size, void* d_ws, size_t ws_size,
                              hipStream_t stream)
{
    const float* hidden = (const float*)d_in[0];
    const float* kvp    = (const float*)d_in[1];
    const float* cosp   = (const float*)d_in[7];
    const float* sinp   = (const float*)d_in[8];
    const float* Wq     = (const float*)d_in[9];
    const float* Wk     = (const float*)d_in[10];
    const float* Wv     = (const float*)d_in[11];
    const float* Wo     = (const float*)d_in[12];
    const int*   layer  = (const int*)d_in[13];

    char* ws = (char*)d_ws;
    f16* w16  = (f16*)ws;                   // 48 MB: Wqkv, later Wo (32 MB)
    f16* h16  = (f16*)(ws + 50331648);      //  8 MB: hidden f16; later oh0
    f16* ck   = (f16*)(ws + 58720256);      //  6 MB K cache; +cv start = oh1 (8 MB)
    f16* cv   = (f16*)(ws + 65011712);      //  6 MB V cache
    f16* obuf = (f16*)(ws + 71303168);      //  8 MB: k/v split-K halves, then attn out

    f16* qh   = (f16*)d_out;                // 16 MB: q halves; half0 becomes q16
    f16* kh   = obuf;                       // 2 x 1,048,576 f16
    f16* vh   = obuf + 2097152;             // 2 x 1,048,576 f16
    f16* oh0  = h16;                        // o-proj partial 0 (8 MB)
    f16* oh1  = (f16*)(ws + 58720256);      // o-proj partial 1 (8 MB, over ck/cv head)

    // 1) fp32 -> fp16 conversions (hidden + Wq + Wk + Wv)
    cvt_all<<<28672, 256, 0, stream>>>(hidden, Wq, Wk, Wv, h16, w16);

    // 2) fused QKV projection, split-K=2 (768 blocks, balanced 3/CU)
    gemm_f16<0><<<dim3(48, 8, 2), 256, 0, stream>>>(
        h16, w16, qh, kh, vh, 1024, 6144, 4096);

    // 3) Wo cvt + sum-halves + RoPE q/k + cache convert + new-V scatter
    aux_all<<<22272, 256, 0, stream>>>(Wo, w16, qh, kh, vh, cosp, sinp,
                                       ck, kvp, layer, cv);

    // 4) flash attention (round-6 structure; q16 = qh half0)
    attn_f16<<<dim3(512), 256, 0, stream>>>(qh, ck, cv, obuf);

    // 5) output projection, split-K=2 (512 blocks, 2/CU) -> fp16 partials
    gemm_f16<1><<<dim3(32, 8, 2), 256, 0, stream>>>(
        obuf, w16, oh0, oh1, nullptr, 1024, 4096, 4096);

    // 6) sum halves -> d_out fp32
    sum2<<<2048, 256, 0, stream>>>(oh0, oh1, (float*)d_out);
}